// Round 17
// baseline (150.987 us; speedup 1.0000x reference)
//
#include <hip/hip_runtime.h>
#include <hip/hip_bf16.h>

typedef short bf16x8 __attribute__((ext_vector_type(8)));
typedef float f32x4 __attribute__((ext_vector_type(4)));
typedef _Float16 half4 __attribute__((ext_vector_type(4)));

__device__ __forceinline__ short f2bf(float f) {
    union { float f; unsigned u; } v; v.f = f;
    unsigned r = (v.u + 0x7FFFu + ((v.u >> 16) & 1u)) >> 16;
    return (short)r;
}

__device__ __forceinline__ float selu_f(float x) {
    const float scale = 1.0507009873554805f;
    const float sa = 1.0507009873554805f * 1.6732632423543772f;
    return x > 0.f ? scale * x : sa * (__expf(x) - 1.f);
}

// ---------------------------------------------------------------------------
// Kernel 1 (merged prep): blocks 0-511: cbias; 512-767: w1img; 768-783: wvec
// ---------------------------------------------------------------------------
__global__ void __launch_bounds__(512) prep_all_kernel(
    const float* __restrict__ c, const int* __restrict__ lat_idx,
    const int* __restrict__ lon_idx,
    const float* __restrict__ f2W1, const float* __restrict__ f2b1,
    const float* __restrict__ f2W2, const float* __restrict__ f2b2,
    const float* __restrict__ fW1, const float* __restrict__ fb1,
    const float* __restrict__ fW21, const float* __restrict__ fW22,
    short* __restrict__ w1img, _Float16* __restrict__ wvec,
    float* __restrict__ cbias)
{
    const int bid = blockIdx.x;
    const int t = threadIdx.x;

    if (bid < 512) {
        __shared__ int cells[64];
        __shared__ float ctraj[128];
        __shared__ float hbuf[256];
        __shared__ float ctrf[128];
        const int b = bid;

        if (t < 64) cells[t] = lat_idx[b * 64 + t] * 17 + lon_idx[b * 64 + t];
        __syncthreads();

        if (t < 128) {
            float s = 0.f;
            #pragma unroll 8
            for (int j = 0; j < 64; ++j) s += c[t * 289 + cells[j]];
            ctraj[t] = s * (1.f / 64.f);
        }
        __syncthreads();

        if (t < 256) {
            float acc = f2b1[t];
            #pragma unroll 8
            for (int i = 0; i < 128; ++i) acc += ctraj[i] * f2W1[i * 256 + t];
            hbuf[t] = selu_f(acc);
        }
        __syncthreads();

        if (t < 128) {
            float acc = f2b2[t];
            #pragma unroll 8
            for (int i = 0; i < 256; ++i) acc += hbuf[i] * f2W2[i * 128 + t];
            ctrf[t] = acc;
        }
        __syncthreads();

        float acc = fb1[t];
        #pragma unroll 8
        for (int i = 0; i < 128; ++i) acc += ctrf[i] * fW1[(256 + i) * 512 + t];
        cbias[b * 512 + t] = acc;
    } else if (bid < 768) {
        int I = (bid - 512) * 512 + t;        // 0..131071
        int e = I & 7;
        int lane = (I >> 3) & 63;
        int cg = (I >> 9) & 31;
        int kc = I >> 14;
        int col = cg * 16 + (lane & 15);
        int k = kc * 32 + ((lane >> 4) << 3) + e;
        w1img[I] = f2bf(fW1[k * 512 + col]);
    } else {
        int I = (bid - 768) * 512 + t;        // 0..8191
        int e = I & 3;
        int lane = (I >> 2) & 63;
        int nc = I >> 8;
        int l15 = lane & 15, hi = lane >> 4;
        int n = nc * 16 + hi * 4 + e;
        float v = (l15 == 0) ? fW21[n] : (l15 == 1 ? fW22[n] : 0.f);
        wvec[I] = (_Float16)v;
    }
}

// ---------------------------------------------------------------------------
// Kernel 2: PERSISTENT fused GEMM (K=256) + selu + MFMA reduce.
// 512 blocks (one per b, exactly 2/CU) x 512 threads (8 waves, 64x64 tiles).
// Each block loops its b's 4 s-quarters; the loop body is VERBATIM R16 —
// all per-quarter state (acc, bN, cbf, wv, rd) lives inside the loop so the
// register profile stays 64 VGPR + 64 AGPR (no R11-style hoist/spill).
// Mechanism under test: amortize per-block-execution fixed costs 8x -> 2x
// per CU; B slices L1-warm for quarters 2-4.
// ---------------------------------------------------------------------------
__global__ void __launch_bounds__(512, 4) fused_gemm_kernel(
    const float* __restrict__ rho, const short* __restrict__ w1img,
    const float* __restrict__ cbias, const _Float16* __restrict__ wvec,
    float* __restrict__ plm, float* __restrict__ plv)
{
    __shared__ __align__(16) char smA[36864];   // A 32KB | redM 2KB | redV 2KB

    const int tid  = threadIdx.x;
    const int lane = tid & 63;
    const int w    = tid >> 6;      // 0..7
    const int l15  = lane & 15;
    const int hi   = lane >> 4;     // 0..3

    const int b = blockIdx.x;

    const int kc_w = (tid >> 2) & 7;
    const int hi_w = tid & 3;
    const int sw_w = (tid >> 5) ^ (tid & 15);
    const char* bp = (const char*)w1img + w * 4096 + lane * 16;
    float* redM = (float*)(smA + 32768);   // [8][64]
    float* redV = (float*)(smA + 34816);   // [8][64]

    #pragma unroll 1
    for (int q = 0; q < 4; ++q) {
        const int s0 = q << 6;

        // ---- stage A: coalesced reads -> cvt_pk -> swizzled frag-major ----
        {
            const float* src = rho + (size_t)(b * 256 + s0) * 256 + tid * 8;
            #pragma unroll
            for (int j = 0; j < 4; ++j) {
                float4 f0 = *(const float4*)(src + j * 4096);
                float4 f1 = *(const float4*)(src + j * 4096 + 4);
                union { bf16x8 h; unsigned u[4]; } pk;
                asm("v_cvt_pk_bf16_f32 %0, %1, %2" : "=v"(pk.u[0]) : "v"(f0.x), "v"(f0.y));
                asm("v_cvt_pk_bf16_f32 %0, %1, %2" : "=v"(pk.u[1]) : "v"(f0.z), "v"(f0.w));
                asm("v_cvt_pk_bf16_f32 %0, %1, %2" : "=v"(pk.u[2]) : "v"(f1.x), "v"(f1.y));
                asm("v_cvt_pk_bf16_f32 %0, %1, %2" : "=v"(pk.u[3]) : "v"(f1.z), "v"(f1.w));
                int slot = (kc_w * 4 + j) * 64 + hi_w * 16 + sw_w;
                *(bf16x8*)(smA + (slot << 4)) = pk.h;
            }
        }
        __syncthreads();   // A(q) visible; prior merge also complete

        f32x4 acc[4][4];
        #pragma unroll
        for (int nf = 0; nf < 4; ++nf)
            #pragma unroll
            for (int sf = 0; sf < 4; ++sf)
                acc[nf][sf] = (f32x4){0.f, 0.f, 0.f, 0.f};

        bf16x8 bN[4];
        #pragma unroll
        for (int nf = 0; nf < 4; ++nf)
            bN[nf] = *(const bf16x8*)(bp + nf * 1024);

        #pragma unroll
        for (int kc = 0; kc < 8; ++kc) {
            bf16x8 bC[4];
            #pragma unroll
            for (int nf = 0; nf < 4; ++nf) bC[nf] = bN[nf];
            if (kc < 7) {
                #pragma unroll
                for (int nf = 0; nf < 4; ++nf)
                    bN[nf] = *(const bf16x8*)(bp + (size_t)(kc + 1) * 32768 + nf * 1024);
            }
            const int sw_r = l15 ^ (((kc & 3) << 2) | hi);
            const char* ab = smA + ((kc * 256 + hi * 16 + sw_r) << 4);
            bf16x8 aF[4];
            #pragma unroll
            for (int sf = 0; sf < 4; ++sf)
                aF[sf] = *(const bf16x8*)(ab + sf * 1024);
            #pragma unroll
            for (int nf = 0; nf < 4; ++nf)
                #pragma unroll
                for (int sf = 0; sf < 4; ++sf)
                    acc[nf][sf] = __builtin_amdgcn_mfma_f32_16x16x32_bf16(
                        bC[nf], aF[sf], acc[nf][sf], 0, 0, 0);
        }

        // ---- epilogue: selu(acc + cbias) -> f16 frags -> reduce MFMA ----
        f32x4 rd[4];
        #pragma unroll
        for (int sf = 0; sf < 4; ++sf) rd[sf] = (f32x4){0.f, 0.f, 0.f, 0.f};

        #pragma unroll
        for (int nf = 0; nf < 4; ++nf) {
            f32x4 cbf = *(const f32x4*)(cbias + b * 512 + w * 64 + nf * 16 + hi * 4);
            half4 wv = *(const half4*)(wvec + (size_t)(w * 4 + nf) * 256 + lane * 4);
            #pragma unroll
            for (int sf = 0; sf < 4; ++sf) {
                half4 pa;
                #pragma unroll
                for (int qq = 0; qq < 4; ++qq)
                    pa[qq] = (_Float16)selu_f(acc[nf][sf][qq] + cbf[qq]);
                rd[sf] = __builtin_amdgcn_mfma_f32_16x16x16f16(pa, wv, rd[sf], 0, 0, 0);
            }
        }

        if (l15 == 0) {
            #pragma unroll
            for (int sf = 0; sf < 4; ++sf)
                *(f32x4*)&redM[w * 64 + sf * 16 + hi * 4] = rd[sf];
        } else if (l15 == 1) {
            #pragma unroll
            for (int sf = 0; sf < 4; ++sf)
                *(f32x4*)&redV[w * 64 + sf * 16 + hi * 4] = rd[sf];
        }

        __syncthreads();   // red complete; all K-loops done (next stage safe)
        size_t obase = (size_t)b * 256 + s0;
        if (tid < 64) {
            float s = 0.f;
            #pragma unroll
            for (int j = 0; j < 8; ++j) s += redM[j * 64 + tid];
            plm[obase + tid] = s;
        } else if (tid < 128) {
            int rr = tid - 64;
            float s = 0.f;
            #pragma unroll
            for (int j = 0; j < 8; ++j) s += redV[j * 64 + rr];
            plv[obase + rr] = s;
        }
        // next iteration's stage writes smA[0,32768) (disjoint from red);
        // its __syncthreads() orders merge-readers vs the next red-write.
    }
}

// ---------------------------------------------------------------------------
// Kernel 3: per-b logsumexp over S=256 and final outputs (1 wave per b)
// ---------------------------------------------------------------------------
__global__ void __launch_bounds__(64) finalize_kernel(
    const float* __restrict__ plm, const float* __restrict__ plv,
    const float* __restrict__ w, const float* __restrict__ l,
    const float* __restrict__ b21p, const float* __restrict__ b22p,
    float* __restrict__ out)
{
    const int b = blockIdx.x;
    const int lane = threadIdx.x;
    const float b21 = b21p[0], b22 = b22p[0];

    float a1[4], a2[4];
    float m1 = -1e30f, m2 = -1e30f;
    #pragma unroll
    for (int i = 0; i < 4; ++i) {
        int s = i * 64 + lane;
        float lw = logf(w[b * 256 + s]);
        a1[i] = plm[b * 256 + s] + b21 + lw;
        a2[i] = plv[b * 256 + s] + b22 + 2.f * lw;
        m1 = fmaxf(m1, a1[i]);
        m2 = fmaxf(m2, a2[i]);
    }
    #pragma unroll
    for (int m = 1; m < 64; m <<= 1) {
        m1 = fmaxf(m1, __shfl_xor(m1, m));
        m2 = fmaxf(m2, __shfl_xor(m2, m));
    }
    float s1 = 0.f, s2 = 0.f;
    #pragma unroll
    for (int i = 0; i < 4; ++i) {
        s1 += expf(a1[i] - m1);
        s2 += expf(a2[i] - m2);
    }
    #pragma unroll
    for (int m = 1; m < 64; m <<= 1) {
        s1 += __shfl_xor(s1, m);
        s2 += __shfl_xor(s2, m);
    }
    if (lane == 0) {
        float lm_agg = m1 + logf(s1);
        float lv_agg = m2 + logf(s2);
        float logl = logf(l[b]);
        out[b]       = logl - lm_agg;
        out[512 + b] = logl - 3.f * lm_agg - lv_agg;
    }
}

extern "C" void kernel_launch(void* const* d_in, const int* in_sizes, int n_in,
                              void* d_out, int out_size, void* d_ws, size_t ws_size,
                              hipStream_t stream) {
    const float* rho     = (const float*)d_in[0];
    const float* c       = (const float*)d_in[1];
    const float* w       = (const float*)d_in[2];
    const float* l       = (const float*)d_in[3];
    // d_in[4] = roads (unused by the reference)
    const int*   lon_idx = (const int*)d_in[5];
    const int*   lat_idx = (const int*)d_in[6];
    const float* f2W1    = (const float*)d_in[7];
    const float* f2b1    = (const float*)d_in[8];
    const float* f2W2    = (const float*)d_in[9];
    const float* f2b2    = (const float*)d_in[10];
    const float* fW1     = (const float*)d_in[11];
    const float* fb1     = (const float*)d_in[12];
    const float* fW21    = (const float*)d_in[13];
    const float* fb21    = (const float*)d_in[14];
    const float* fW22    = (const float*)d_in[15];
    const float* fb22    = (const float*)d_in[16];
    float* out = (float*)d_out;

    char* ws = (char*)d_ws;
    float*     cbias = (float*)(ws);               // 1048576 B
    short*     w1img = (short*)(ws + 1048576);     //  262144 B
    float*     plm   = (float*)(ws + 1310720);     //  524288 B
    float*     plv   = (float*)(ws + 1835008);     //  524288 B
    _Float16*  wvec  = (_Float16*)(ws + 2359296);  //   16384 B

    prep_all_kernel<<<784, 512, 0, stream>>>(c, lat_idx, lon_idx,
                                             f2W1, f2b1, f2W2, f2b2,
                                             fW1, fb1, fW21, fW22,
                                             w1img, wvec, cbias);
    fused_gemm_kernel<<<512, 512, 0, stream>>>(rho, w1img, cbias, wvec,
                                               plm, plv);
    finalize_kernel<<<512, 64, 0, stream>>>(plm, plv, w, l, fb21, fb22, out);
}

// Round 18
// 92.422 us; speedup vs baseline: 1.6337x; 1.6337x over previous
//
#include <hip/hip_runtime.h>
#include <hip/hip_bf16.h>

typedef short bf16x8 __attribute__((ext_vector_type(8)));
typedef float f32x4 __attribute__((ext_vector_type(4)));
typedef _Float16 half4 __attribute__((ext_vector_type(4)));

__device__ __forceinline__ short f2bf(float f) {
    union { float f; unsigned u; } v; v.f = f;
    unsigned r = (v.u + 0x7FFFu + ((v.u >> 16) & 1u)) >> 16;
    return (short)r;
}

__device__ __forceinline__ float selu_f(float x) {
    const float scale = 1.0507009873554805f;
    const float sa = 1.0507009873554805f * 1.6732632423543772f;
    return x > 0.f ? scale * x : sa * (__expf(x) - 1.f);
}

// ---------------------------------------------------------------------------
// Kernel 1 (merged prep): blocks 0-511: cbias; 512-767: w1img; 768-783: wvec
// ---------------------------------------------------------------------------
__global__ void __launch_bounds__(512) prep_all_kernel(
    const float* __restrict__ c, const int* __restrict__ lat_idx,
    const int* __restrict__ lon_idx,
    const float* __restrict__ f2W1, const float* __restrict__ f2b1,
    const float* __restrict__ f2W2, const float* __restrict__ f2b2,
    const float* __restrict__ fW1, const float* __restrict__ fb1,
    const float* __restrict__ fW21, const float* __restrict__ fW22,
    short* __restrict__ w1img, _Float16* __restrict__ wvec,
    float* __restrict__ cbias)
{
    const int bid = blockIdx.x;
    const int t = threadIdx.x;

    if (bid < 512) {
        __shared__ int cells[64];
        __shared__ float ctraj[128];
        __shared__ float hbuf[256];
        __shared__ float ctrf[128];
        const int b = bid;

        if (t < 64) cells[t] = lat_idx[b * 64 + t] * 17 + lon_idx[b * 64 + t];
        __syncthreads();

        if (t < 128) {
            float s = 0.f;
            #pragma unroll 8
            for (int j = 0; j < 64; ++j) s += c[t * 289 + cells[j]];
            ctraj[t] = s * (1.f / 64.f);
        }
        __syncthreads();

        if (t < 256) {
            float acc = f2b1[t];
            #pragma unroll 8
            for (int i = 0; i < 128; ++i) acc += ctraj[i] * f2W1[i * 256 + t];
            hbuf[t] = selu_f(acc);
        }
        __syncthreads();

        if (t < 128) {
            float acc = f2b2[t];
            #pragma unroll 8
            for (int i = 0; i < 256; ++i) acc += hbuf[i] * f2W2[i * 128 + t];
            ctrf[t] = acc;
        }
        __syncthreads();

        float acc = fb1[t];
        #pragma unroll 8
        for (int i = 0; i < 128; ++i) acc += ctrf[i] * fW1[(256 + i) * 512 + t];
        cbias[b * 512 + t] = acc;
    } else if (bid < 768) {
        int I = (bid - 512) * 512 + t;        // 0..131071
        int e = I & 7;
        int lane = (I >> 3) & 63;
        int cg = (I >> 9) & 31;
        int kc = I >> 14;
        int col = cg * 16 + (lane & 15);
        int k = kc * 32 + ((lane >> 4) << 3) + e;
        w1img[I] = f2bf(fW1[k * 512 + col]);
    } else {
        int I = (bid - 768) * 512 + t;        // 0..8191
        int e = I & 3;
        int lane = (I >> 2) & 63;
        int nc = I >> 8;
        int l15 = lane & 15, hi = lane >> 4;
        int n = nc * 16 + hi * 4 + e;
        float v = (l15 == 0) ? fW21[n] : (l15 == 1 ? fW22[n] : 0.f);
        wvec[I] = (_Float16)v;
    }
}

// ---------------------------------------------------------------------------
// Kernel 2: fused GEMM (K=256) + selu + MFMA reduce (best-measured config).
// 2048 blocks (b x s-quarter) x 512 threads (8 waves, each 64 rows x 64 cols
// of the 64x512 block tile; all waves share the A rows).
// A: staged once (coalesced 32B/lane reads -> cvt_pk -> XOR-swizzled
//    fragment-major LDS, conflict-free both sides); one barrier.
// B: per-wave global reg-dbuf (1-deep) from the L2-resident image.
// Zero barriers in the K-loop. f16-MFMA reduce epilogue (no shuffles).
// Registers: 64 VGPR + 64 AGPR = exactly the (512,4) cap — do not add state;
// any structural wrapper (persistence/bigger acc/deeper prefetch) spills.
// ---------------------------------------------------------------------------
__global__ void __launch_bounds__(512, 4) fused_gemm_kernel(
    const float* __restrict__ rho, const short* __restrict__ w1img,
    const float* __restrict__ cbias, const _Float16* __restrict__ wvec,
    float* __restrict__ plm, float* __restrict__ plv)
{
    __shared__ __align__(16) char smA[36864];   // A 32KB | redM 2KB | redV 2KB

    const int tid  = threadIdx.x;
    const int lane = tid & 63;
    const int w    = tid >> 6;      // 0..7
    const int l15  = lane & 15;
    const int hi   = lane >> 4;     // 0..3

    const int b  = blockIdx.x >> 2;
    const int s0 = (blockIdx.x & 3) << 6;

    // ---- stage A once: coalesced reads -> cvt_pk -> swizzled frag-major ----
    {
        const float* src = rho + (size_t)(b * 256 + s0) * 256 + tid * 8;
        const int kc_w = (tid >> 2) & 7;
        const int hi_w = tid & 3;
        const int sw_w = (tid >> 5) ^ (tid & 15);
        #pragma unroll
        for (int j = 0; j < 4; ++j) {
            float4 f0 = *(const float4*)(src + j * 4096);
            float4 f1 = *(const float4*)(src + j * 4096 + 4);
            union { bf16x8 h; unsigned u[4]; } pk;
            asm("v_cvt_pk_bf16_f32 %0, %1, %2" : "=v"(pk.u[0]) : "v"(f0.x), "v"(f0.y));
            asm("v_cvt_pk_bf16_f32 %0, %1, %2" : "=v"(pk.u[1]) : "v"(f0.z), "v"(f0.w));
            asm("v_cvt_pk_bf16_f32 %0, %1, %2" : "=v"(pk.u[2]) : "v"(f1.x), "v"(f1.y));
            asm("v_cvt_pk_bf16_f32 %0, %1, %2" : "=v"(pk.u[3]) : "v"(f1.z), "v"(f1.w));
            int slot = (kc_w * 4 + j) * 64 + hi_w * 16 + sw_w;
            *(bf16x8*)(smA + (slot << 4)) = pk.h;
        }
    }
    __syncthreads();   // only block-wide barrier before the epilogue

    f32x4 acc[4][4];   // [nf][sf] (C^T, swapped operands)
    #pragma unroll
    for (int nf = 0; nf < 4; ++nf)
        #pragma unroll
        for (int sf = 0; sf < 4; ++sf)
            acc[nf][sf] = (f32x4){0.f, 0.f, 0.f, 0.f};

    // wave w owns cols w*64..w*64+63: col-groups cg = kc*32 + w*4 + nf
    const char* bp = (const char*)w1img + w * 4096 + lane * 16;

    bf16x8 bN[4];
    #pragma unroll
    for (int nf = 0; nf < 4; ++nf)
        bN[nf] = *(const bf16x8*)(bp + nf * 1024);

    #pragma unroll
    for (int kc = 0; kc < 8; ++kc) {
        bf16x8 bC[4];
        #pragma unroll
        for (int nf = 0; nf < 4; ++nf) bC[nf] = bN[nf];
        if (kc < 7) {
            #pragma unroll
            for (int nf = 0; nf < 4; ++nf)
                bN[nf] = *(const bf16x8*)(bp + (size_t)(kc + 1) * 32768 + nf * 1024);
        }
        // swizzled A-fragment reads (conflict-free)
        const int sw_r = l15 ^ (((kc & 3) << 2) | hi);
        const char* ab = smA + ((kc * 256 + hi * 16 + sw_r) << 4);
        bf16x8 aF[4];
        #pragma unroll
        for (int sf = 0; sf < 4; ++sf)
            aF[sf] = *(const bf16x8*)(ab + sf * 1024);
        #pragma unroll
        for (int nf = 0; nf < 4; ++nf)
            #pragma unroll
            for (int sf = 0; sf < 4; ++sf)
                acc[nf][sf] = __builtin_amdgcn_mfma_f32_16x16x32_bf16(
                    bC[nf], aF[sf], acc[nf][sf], 0, 0, 0);
    }

    // ---- epilogue: selu(acc + cbias) -> f16 frags -> 16x16x16 reduce MFMA ----
    f32x4 rd[4];
    #pragma unroll
    for (int sf = 0; sf < 4; ++sf) rd[sf] = (f32x4){0.f, 0.f, 0.f, 0.f};

    #pragma unroll
    for (int nf = 0; nf < 4; ++nf) {
        f32x4 cbf = *(const f32x4*)(cbias + b * 512 + w * 64 + nf * 16 + hi * 4);
        half4 wv = *(const half4*)(wvec + (size_t)(w * 4 + nf) * 256 + lane * 4);
        #pragma unroll
        for (int sf = 0; sf < 4; ++sf) {
            half4 pa;
            #pragma unroll
            for (int q = 0; q < 4; ++q)
                pa[q] = (_Float16)selu_f(acc[nf][sf][q] + cbf[q]);
            rd[sf] = __builtin_amdgcn_mfma_f32_16x16x16f16(pa, wv, rd[sf], 0, 0, 0);
        }
    }

    float* redM = (float*)(smA + 32768);   // [8][64]
    float* redV = (float*)(smA + 34816);   // [8][64]
    if (l15 == 0) {
        #pragma unroll
        for (int sf = 0; sf < 4; ++sf)
            *(f32x4*)&redM[w * 64 + sf * 16 + hi * 4] = rd[sf];
    } else if (l15 == 1) {
        #pragma unroll
        for (int sf = 0; sf < 4; ++sf)
            *(f32x4*)&redV[w * 64 + sf * 16 + hi * 4] = rd[sf];
    }

    __syncthreads();
    size_t obase = (size_t)b * 256 + s0;
    if (tid < 64) {
        float s = 0.f;
        #pragma unroll
        for (int j = 0; j < 8; ++j) s += redM[j * 64 + tid];
        plm[obase + tid] = s;
    } else if (tid < 128) {
        int rr = tid - 64;
        float s = 0.f;
        #pragma unroll
        for (int j = 0; j < 8; ++j) s += redV[j * 64 + rr];
        plv[obase + rr] = s;
    }
}

// ---------------------------------------------------------------------------
// Kernel 3: per-b logsumexp over S=256 and final outputs (1 wave per b)
// ---------------------------------------------------------------------------
__global__ void __launch_bounds__(64) finalize_kernel(
    const float* __restrict__ plm, const float* __restrict__ plv,
    const float* __restrict__ w, const float* __restrict__ l,
    const float* __restrict__ b21p, const float* __restrict__ b22p,
    float* __restrict__ out)
{
    const int b = blockIdx.x;
    const int lane = threadIdx.x;
    const float b21 = b21p[0], b22 = b22p[0];

    float a1[4], a2[4];
    float m1 = -1e30f, m2 = -1e30f;
    #pragma unroll
    for (int i = 0; i < 4; ++i) {
        int s = i * 64 + lane;
        float lw = logf(w[b * 256 + s]);
        a1[i] = plm[b * 256 + s] + b21 + lw;
        a2[i] = plv[b * 256 + s] + b22 + 2.f * lw;
        m1 = fmaxf(m1, a1[i]);
        m2 = fmaxf(m2, a2[i]);
    }
    #pragma unroll
    for (int m = 1; m < 64; m <<= 1) {
        m1 = fmaxf(m1, __shfl_xor(m1, m));
        m2 = fmaxf(m2, __shfl_xor(m2, m));
    }
    float s1 = 0.f, s2 = 0.f;
    #pragma unroll
    for (int i = 0; i < 4; ++i) {
        s1 += expf(a1[i] - m1);
        s2 += expf(a2[i] - m2);
    }
    #pragma unroll
    for (int m = 1; m < 64; m <<= 1) {
        s1 += __shfl_xor(s1, m);
        s2 += __shfl_xor(s2, m);
    }
    if (lane == 0) {
        float lm_agg = m1 + logf(s1);
        float lv_agg = m2 + logf(s2);
        float logl = logf(l[b]);
        out[b]       = logl - lm_agg;
        out[512 + b] = logl - 3.f * lm_agg - lv_agg;
    }
}

extern "C" void kernel_launch(void* const* d_in, const int* in_sizes, int n_in,
                              void* d_out, int out_size, void* d_ws, size_t ws_size,
                              hipStream_t stream) {
    const float* rho     = (const float*)d_in[0];
    const float* c       = (const float*)d_in[1];
    const float* w       = (const float*)d_in[2];
    const float* l       = (const float*)d_in[3];
    // d_in[4] = roads (unused by the reference)
    const int*   lon_idx = (const int*)d_in[5];
    const int*   lat_idx = (const int*)d_in[6];
    const float* f2W1    = (const float*)d_in[7];
    const float* f2b1    = (const float*)d_in[8];
    const float* f2W2    = (const float*)d_in[9];
    const float* f2b2    = (const float*)d_in[10];
    const float* fW1     = (const float*)d_in[11];
    const float* fb1     = (const float*)d_in[12];
    const float* fW21    = (const float*)d_in[13];
    const float* fb21    = (const float*)d_in[14];
    const float* fW22    = (const float*)d_in[15];
    const float* fb22    = (const float*)d_in[16];
    float* out = (float*)d_out;

    char* ws = (char*)d_ws;
    float*     cbias = (float*)(ws);               // 1048576 B
    short*     w1img = (short*)(ws + 1048576);     //  262144 B
    float*     plm   = (float*)(ws + 1310720);     //  524288 B
    float*     plv   = (float*)(ws + 1835008);     //  524288 B
    _Float16*  wvec  = (_Float16*)(ws + 2359296);  //   16384 B

    prep_all_kernel<<<784, 512, 0, stream>>>(c, lat_idx, lon_idx,
                                             f2W1, f2b1, f2W2, f2b2,
                                             fW1, fb1, fW21, fW22,
                                             w1img, wvec, cbias);
    fused_gemm_kernel<<<2048, 512, 0, stream>>>(rho, w1img, cbias, wvec,
                                                plm, plv);
    finalize_kernel<<<512, 64, 0, stream>>>(plm, plv, w, l, fb21, fb22, out);
}